// Round 1
// baseline (6925.231 us; speedup 1.0000x reference)
//
#include <hip/hip_runtime.h>

// Problem constants (fixed by the reference)
#define NB 4
#define NT 2048
#define NC 1024
#define NE 8
#define NK 2
#define NH 4096
#define NCAP 2048
#define NTOK (NB * NT)          // 8192
#define NFLAT (NTOK * NK)       // 16384

#define TM 128
#define TN 128
#define TBK 16

// ---------------------------------------------------------------------------
// Generic fp32 GEMM: C[M,N] = act(A[M,K] @ B[K,N] + bias[N]); batched via
// blockIdx.z with element strides esA/esB/esBias/esC.
// 128x128 tile, 256 threads, 8x8 microtile, BK=16, float4 staging.
// ---------------------------------------------------------------------------
__global__ __launch_bounds__(256)
void gemm_bias_act(const float* __restrict__ A, const float* __restrict__ B,
                   const float* __restrict__ bias, float* __restrict__ C,
                   int M, int N, int K, int do_relu,
                   size_t esA, size_t esB, size_t esBias, size_t esC)
{
    const int e = blockIdx.z;
    A    += (size_t)e * esA;
    B    += (size_t)e * esB;
    bias += (size_t)e * esBias;
    C    += (size_t)e * esC;

    __shared__ float As[TBK][TM];
    __shared__ float Bs[TBK][TN];

    const int bm = blockIdx.y * TM;
    const int bn = blockIdx.x * TN;
    const int tid = threadIdx.x;
    const int tx = tid & 15;   // output col group
    const int ty = tid >> 4;   // output row group

    float acc[8][8];
    #pragma unroll
    for (int i = 0; i < 8; ++i)
        #pragma unroll
        for (int j = 0; j < 8; ++j) acc[i][j] = 0.f;

    for (int k0 = 0; k0 < K; k0 += TBK) {
        // Stage A tile (128 rows x 16 k), transposed into As[k][m]
        #pragma unroll
        for (int i = 0; i < 2; ++i) {
            int idx = tid + 256 * i;      // 0..511 float4s
            int r   = idx >> 2;           // 0..127
            int c4  = idx & 3;            // 0..3
            float4 av = *(const float4*)(A + (size_t)(bm + r) * K + k0 + c4 * 4);
            As[c4 * 4 + 0][r] = av.x;
            As[c4 * 4 + 1][r] = av.y;
            As[c4 * 4 + 2][r] = av.z;
            As[c4 * 4 + 3][r] = av.w;
        }
        // Stage B tile (16 k x 128 cols), direct
        #pragma unroll
        for (int i = 0; i < 2; ++i) {
            int idx = tid + 256 * i;      // 0..511 float4s
            int r   = idx >> 5;           // 0..15
            int c4  = idx & 31;           // 0..31
            *(float4*)(&Bs[r][c4 * 4]) =
                *(const float4*)(B + (size_t)(k0 + r) * N + bn + c4 * 4);
        }
        __syncthreads();

        #pragma unroll
        for (int kk = 0; kk < TBK; ++kk) {
            float a[8], b[8];
            *(float4*)(a)     = *(const float4*)(&As[kk][ty * 8]);
            *(float4*)(a + 4) = *(const float4*)(&As[kk][ty * 8 + 4]);
            *(float4*)(b)     = *(const float4*)(&Bs[kk][tx * 8]);
            *(float4*)(b + 4) = *(const float4*)(&Bs[kk][tx * 8 + 4]);
            #pragma unroll
            for (int i = 0; i < 8; ++i)
                #pragma unroll
                for (int j = 0; j < 8; ++j)
                    acc[i][j] = fmaf(a[i], b[j], acc[i][j]);
        }
        __syncthreads();
    }

    // Epilogue: bias + optional relu, vectorized stores
    #pragma unroll
    for (int i = 0; i < 8; ++i) {
        int row = bm + ty * 8 + i;
        #pragma unroll
        for (int j4 = 0; j4 < 2; ++j4) {
            int col = bn + tx * 8 + j4 * 4;
            float4 bv = *(const float4*)(bias + col);
            float4 v;
            v.x = acc[i][j4 * 4 + 0] + bv.x;
            v.y = acc[i][j4 * 4 + 1] + bv.y;
            v.z = acc[i][j4 * 4 + 2] + bv.z;
            v.w = acc[i][j4 * 4 + 3] + bv.w;
            if (do_relu) {
                v.x = fmaxf(v.x, 0.f); v.y = fmaxf(v.y, 0.f);
                v.z = fmaxf(v.z, 0.f); v.w = fmaxf(v.w, 0.f);
            }
            *(float4*)(C + (size_t)row * N + col) = v;
        }
    }
}

// ---------------------------------------------------------------------------
// Fused logits (h2 @ rw3 + rb3), softmax over 8 experts, top-2 select.
// One block per token. Tie-break: lowest index (matches jax.lax.top_k).
// ---------------------------------------------------------------------------
__global__ __launch_bounds__(256)
void logits_top2(const float* __restrict__ h2, const float* __restrict__ rw3,
                 const float* __restrict__ rb3,
                 int* __restrict__ topk_e, float* __restrict__ topk_p)
{
    const int row = blockIdx.x;
    const int tid = threadIdx.x;
    __shared__ float red[256][8];

    float acc[8];
    #pragma unroll
    for (int e = 0; e < 8; ++e) acc[e] = 0.f;

    const float* hr = h2 + (size_t)row * NH;
    for (int k = tid; k < NH; k += 256) {
        float xv = hr[k];
        float4 w0 = *(const float4*)(rw3 + (size_t)k * 8);
        float4 w1 = *(const float4*)(rw3 + (size_t)k * 8 + 4);
        acc[0] = fmaf(xv, w0.x, acc[0]);
        acc[1] = fmaf(xv, w0.y, acc[1]);
        acc[2] = fmaf(xv, w0.z, acc[2]);
        acc[3] = fmaf(xv, w0.w, acc[3]);
        acc[4] = fmaf(xv, w1.x, acc[4]);
        acc[5] = fmaf(xv, w1.y, acc[5]);
        acc[6] = fmaf(xv, w1.z, acc[6]);
        acc[7] = fmaf(xv, w1.w, acc[7]);
    }
    #pragma unroll
    for (int e = 0; e < 8; ++e) red[tid][e] = acc[e];
    __syncthreads();
    for (int s = 128; s > 0; s >>= 1) {
        if (tid < s) {
            #pragma unroll
            for (int e = 0; e < 8; ++e) red[tid][e] += red[tid + s][e];
        }
        __syncthreads();
    }
    if (tid == 0) {
        float l[8];
        #pragma unroll
        for (int e = 0; e < 8; ++e) l[e] = red[0][e] + rb3[e];
        float mx = l[0];
        #pragma unroll
        for (int e = 1; e < 8; ++e) mx = fmaxf(mx, l[e]);
        float ex[8], sum = 0.f;
        #pragma unroll
        for (int e = 0; e < 8; ++e) { ex[e] = expf(l[e] - mx); sum += ex[e]; }
        float inv = 1.f / sum;
        float p[8];
        #pragma unroll
        for (int e = 0; e < 8; ++e) p[e] = ex[e] * inv;
        int b0 = 0;
        #pragma unroll
        for (int e = 1; e < 8; ++e) if (p[e] > p[b0]) b0 = e;  // strict >: lowest idx on tie
        int b1 = (b0 == 0) ? 1 : 0;
        #pragma unroll
        for (int e = 0; e < 8; ++e)
            if (e != b0 && p[e] > p[b1]) b1 = e;
        topk_e[row * 2 + 0] = b0;
        topk_e[row * 2 + 1] = b1;
        topk_p[row * 2 + 0] = p[b0];
        topk_p[row * 2 + 1] = p[b1];
    }
}

// ---------------------------------------------------------------------------
// Sequential capacity scan over the 16384 flat (token,k) entries.
// pos[i] = # of j<i with same expert. Single block, ballot-based.
// ---------------------------------------------------------------------------
__global__ __launch_bounds__(256)
void scan_pos(const int* __restrict__ topk_e, int* __restrict__ pos)
{
    __shared__ int base[8];
    __shared__ int wavecnt[4][8];
    const int tid = threadIdx.x;
    const int lane = tid & 63;
    const int w = tid >> 6;
    if (tid < 8) base[tid] = 0;
    __syncthreads();

    for (int c = 0; c < NFLAT; c += 256) {
        int e = topk_e[c + tid];
        int myrank = 0;
        #pragma unroll
        for (int ee = 0; ee < 8; ++ee) {
            unsigned long long m = __ballot(e == ee);
            if (e == ee) myrank = __popcll(m & ((1ull << lane) - 1ull));
            if (lane == ee) wavecnt[w][ee] = __popcll(m);
        }
        __syncthreads();
        int p = base[e] + myrank;
        for (int ww = 0; ww < w; ++ww) p += wavecnt[ww][e];
        pos[c + tid] = p;
        __syncthreads();
        if (tid < 8) {
            int t = base[tid];
            #pragma unroll
            for (int ww = 0; ww < 4; ++ww) t += wavecnt[ww][tid];
            base[tid] = t;
        }
        __syncthreads();
    }
}

// ---------------------------------------------------------------------------
__global__ __launch_bounds__(256)
void zero_f4(float4* __restrict__ p)
{
    p[(size_t)blockIdx.x * 256 + threadIdx.x] = make_float4(0.f, 0.f, 0.f, 0.f);
}

// One block per flat entry: copy token row into disp[e][pos] if kept.
__global__ __launch_bounds__(256)
void dispatch_k(const float* __restrict__ x, const int* __restrict__ topk_e,
                const int* __restrict__ pos, float* __restrict__ disp)
{
    const int i = blockIdx.x;
    const int p = pos[i];
    if (p >= NCAP) return;
    const int e = topk_e[i];
    const int token = i >> 1;
    const float4* src = (const float4*)(x + (size_t)token * NC);
    float4* dst = (float4*)(disp + ((size_t)e * NCAP + p) * NC);
    dst[threadIdx.x] = src[threadIdx.x];
}

// One block per token: out[token] = sum_k keep * p_k * eo[e_k][pos_k]
__global__ __launch_bounds__(256)
void combine_k(const float* __restrict__ eo, const int* __restrict__ topk_e,
               const int* __restrict__ pos, const float* __restrict__ topk_p,
               float* __restrict__ out)
{
    const int token = blockIdx.x;
    float4 acc = make_float4(0.f, 0.f, 0.f, 0.f);
    #pragma unroll
    for (int k = 0; k < NK; ++k) {
        int i = token * NK + k;
        int p = pos[i];
        if (p < NCAP) {
            int e = topk_e[i];
            float pr = topk_p[i];
            float4 v = ((const float4*)(eo + ((size_t)e * NCAP + p) * NC))[threadIdx.x];
            acc.x = fmaf(pr, v.x, acc.x);
            acc.y = fmaf(pr, v.y, acc.y);
            acc.z = fmaf(pr, v.z, acc.z);
            acc.w = fmaf(pr, v.w, acc.w);
        }
    }
    ((float4*)(out + (size_t)token * NC))[threadIdx.x] = acc;
}

// ---------------------------------------------------------------------------
extern "C" void kernel_launch(void* const* d_in, const int* in_sizes, int n_in,
                              void* d_out, int out_size, void* d_ws, size_t ws_size,
                              hipStream_t stream)
{
    const float* x   = (const float*)d_in[0];
    const float* rw1 = (const float*)d_in[1];
    const float* rb1 = (const float*)d_in[2];
    const float* rw2 = (const float*)d_in[3];
    const float* rb2 = (const float*)d_in[4];
    const float* rw3 = (const float*)d_in[5];
    const float* rb3 = (const float*)d_in[6];
    const float* ew1 = (const float*)d_in[7];
    const float* eb1 = (const float*)d_in[8];
    const float* ew2 = (const float*)d_in[9];
    const float* eb2 = (const float*)d_in[10];
    float* out = (float*)d_out;

    // Workspace layout (bytes):
    //   [0, 128Mi)        h1   (router hidden 1)        -- later reused: disp [0,64Mi)
    //   [128Mi, 256Mi)    h2   (router hidden 2)        -- dead after logits
    //   [64Mi, 320Mi)     eh   (expert hidden, 8x2048x4096 f32 = 256Mi)
    //   [320Mi, 384Mi)    eo   (expert out, 8x2048x1024 f32 = 64Mi)
    //   [384Mi, ...)      topk_e / topk_p / pos (64KiB each)
    char* ws = (char*)d_ws;
    const size_t MI = 1024ull * 1024ull;
    float* h1   = (float*)(ws);
    float* h2   = (float*)(ws + 128 * MI);
    float* disp = (float*)(ws);
    float* eh   = (float*)(ws + 64 * MI);
    float* eo   = (float*)(ws + 320 * MI);
    int*   topk_e = (int*)  (ws + 384 * MI);
    float* topk_p = (float*)(ws + 384 * MI + 65536);
    int*   pos    = (int*)  (ws + 384 * MI + 131072);

    // Router layer 1: h1 = relu(x @ rw1 + rb1)   [8192x1024 @ 1024x4096]
    gemm_bias_act<<<dim3(NH / TN, NTOK / TM, 1), 256, 0, stream>>>(
        x, rw1, rb1, h1, NTOK, NH, NC, 1, 0, 0, 0, 0);
    // Router layer 2: h2 = relu(h1 @ rw2 + rb2)  [8192x4096 @ 4096x4096]
    gemm_bias_act<<<dim3(NH / TN, NTOK / TM, 1), 256, 0, stream>>>(
        h1, rw2, rb2, h2, NTOK, NH, NH, 1, 0, 0, 0, 0);
    // Logits + softmax + top2
    logits_top2<<<NTOK, 256, 0, stream>>>(h2, rw3, rb3, topk_e, topk_p);
    // Capacity scan
    scan_pos<<<1, 256, 0, stream>>>(topk_e, pos);
    // Zero dispatch buffer (64 MiB = 4194304 float4s)
    zero_f4<<<16384, 256, 0, stream>>>((float4*)disp);
    // Scatter tokens
    dispatch_k<<<NFLAT, 256, 0, stream>>>(x, topk_e, pos, disp);
    // Expert layer 1 (batched over 8 experts): eh = relu(disp @ ew1 + eb1)
    gemm_bias_act<<<dim3(NH / TN, NCAP / TM, NE), 256, 0, stream>>>(
        disp, ew1, eb1, eh, NCAP, NH, NC, 1,
        (size_t)NCAP * NC, (size_t)NC * NH, (size_t)NH, (size_t)NCAP * NH);
    // Expert layer 2: eo = eh @ ew2 + eb2
    gemm_bias_act<<<dim3(NC / TN, NCAP / TM, NE), 256, 0, stream>>>(
        eh, ew2, eb2, eo, NCAP, NC, NH, 0,
        (size_t)NCAP * NH, (size_t)NH * NC, (size_t)NC, (size_t)NCAP * NC);
    // Combine
    combine_k<<<NTOK, 256, 0, stream>>>(eo, topk_e, pos, topk_p, out);
}